// Round 4
// baseline (881.679 us; speedup 1.0000x reference)
//
#include <hip/hip_runtime.h>
#include <float.h>

// VQ: B=32, C=64, H=64, W=64, N_EMBED=512
#define C_DIM   64
#define K_CODES 512
#define HW_BITS 12            // HW = 4096
#define N_TOK   131072
#define WAVES   4
#define KPW     (K_CODES / WAVES)   // 128 codes per wave
#define KSTREAM (KPW / 4)           // 32 codes per stream

// Prep: transpose embed [C][K] -> eT [K][C], and norms[k] = ||e_k||^2.
__global__ __launch_bounds__(256) void vq_prep(const float* __restrict__ embed,
                                               float* __restrict__ eT,
                                               float* __restrict__ norms) {
    int k = blockIdx.x * blockDim.x + threadIdx.x;
    if (k >= K_CODES) return;
    float s = 0.f;
    #pragma unroll
    for (int c = 0; c < C_DIM; ++c) {
        float v = embed[c * K_CODES + k];   // coalesced across k
        eT[k * C_DIM + c] = v;
        s = fmaf(v, v, s);
    }
    norms[k] = s;
}

// Block = 256 threads = 4 waves over the SAME 64 tokens; wave w scans codes
// [128w, 128w+128) as FOUR independent streams (k0+32s) processed together:
// 4x scalar-load pipeline depth, 4x reuse of each f chunk, 16 FMA chains.
__global__ __launch_bounds__(256, 4) void vq_main(const float* __restrict__ x,
                                                  const float* __restrict__ eT,
                                                  const float* __restrict__ norms,
                                                  float* __restrict__ out_qwg,
                                                  float* __restrict__ out_q,
                                                  float* __restrict__ out_ind) {
    const int lane = threadIdx.x & 63;
    const int wvu  = __builtin_amdgcn_readfirstlane((int)(threadIdx.x >> 6)); // uniform
    const int tok  = (blockIdx.x << 6) + lane;
    const int b    = tok >> HW_BITS;
    const int hw   = tok & ((1 << HW_BITS) - 1);

    const float* xb = x + ((size_t)b << 18) + hw;   // b*C*HW + hw

    float f[C_DIM];
    #pragma unroll
    for (int c = 0; c < C_DIM; ++c) f[c] = xb[(size_t)c << HW_BITS];  // coalesced

    const int    k0 = wvu * KPW;
    const float* e0 = eT + ((size_t)(k0 + 0 * KSTREAM) << 6);
    const float* e1 = eT + ((size_t)(k0 + 1 * KSTREAM) << 6);
    const float* e2 = eT + ((size_t)(k0 + 2 * KSTREAM) << 6);
    const float* e3 = eT + ((size_t)(k0 + 3 * KSTREAM) << 6);
    const float* n0 = norms + k0;

    float bA = FLT_MAX, bB = FLT_MAX, bC = FLT_MAX, bD = FLT_MAX;
    int   iA = 0, iB = 0, iC = 0, iD = 0;

    #pragma unroll 1
    for (int kk = 0; kk < KSTREAM; ++kk) {
        const float* p0 = e0 + (kk << 6);   // all wave-uniform -> s_load path
        const float* p1 = e1 + (kk << 6);
        const float* p2 = e2 + (kk << 6);
        const float* p3 = e3 + (kk << 6);
        float a0 = 0.f, a1 = 0.f, a2 = 0.f, a3 = 0.f;
        float b0 = 0.f, b1 = 0.f, b2 = 0.f, b3 = 0.f;
        float c0 = 0.f, c1 = 0.f, c2 = 0.f, c3 = 0.f;
        float d0 = 0.f, d1 = 0.f, d2 = 0.f, d3 = 0.f;
        #pragma unroll
        for (int c = 0; c < C_DIM; c += 4) {
            a0 = fmaf(f[c + 0], p0[c + 0], a0);
            a1 = fmaf(f[c + 1], p0[c + 1], a1);
            a2 = fmaf(f[c + 2], p0[c + 2], a2);
            a3 = fmaf(f[c + 3], p0[c + 3], a3);
            b0 = fmaf(f[c + 0], p1[c + 0], b0);
            b1 = fmaf(f[c + 1], p1[c + 1], b1);
            b2 = fmaf(f[c + 2], p1[c + 2], b2);
            b3 = fmaf(f[c + 3], p1[c + 3], b3);
            c0 = fmaf(f[c + 0], p2[c + 0], c0);
            c1 = fmaf(f[c + 1], p2[c + 1], c1);
            c2 = fmaf(f[c + 2], p2[c + 2], c2);
            c3 = fmaf(f[c + 3], p2[c + 3], c3);
            d0 = fmaf(f[c + 0], p3[c + 0], d0);
            d1 = fmaf(f[c + 1], p3[c + 1], d1);
            d2 = fmaf(f[c + 2], p3[c + 2], d2);
            d3 = fmaf(f[c + 3], p3[c + 3], d3);
        }
        // same reduce order as rounds 1-3 -> bit-identical scores
        float sA = fmaf(-2.f, (a0 + a1) + (a2 + a3), n0[kk + 0 * KSTREAM]);
        float sB = fmaf(-2.f, (b0 + b1) + (b2 + b3), n0[kk + 1 * KSTREAM]);
        float sC = fmaf(-2.f, (c0 + c1) + (c2 + c3), n0[kk + 2 * KSTREAM]);
        float sD = fmaf(-2.f, (d0 + d1) + (d2 + d3), n0[kk + 3 * KSTREAM]);
        if (sA < bA) { bA = sA; iA = kk; }   // strict < = first min per stream
        if (sB < bB) { bB = sB; iB = kk; }
        if (sC < bC) { bC = sC; iC = kk; }
        if (sD < bD) { bD = sD; iD = kk; }
    }

    // merge streams in ascending-index order, strict < -> global first-min
    float best  = bA;
    int   bestk = k0 + iA;
    if (bB < best) { best = bB; bestk = k0 + 1 * KSTREAM + iB; }
    if (bC < best) { best = bC; bestk = k0 + 2 * KSTREAM + iC; }
    if (bD < best) { best = bD; bestk = k0 + 3 * KSTREAM + iD; }

    __shared__ float sS[WAVES][64];
    __shared__ int   sI[WAVES][64];
    sS[wvu][lane] = best;
    sI[wvu][lane] = bestk;
    __syncthreads();

    // every thread recomputes the global winner (deterministic, all agree)
    float gb = sS[0][lane];
    int   gk = sI[0][lane];
    #pragma unroll
    for (int w = 1; w < WAVES; ++w) {       // compile-time w, ascending chunks
        float s = sS[w][lane];
        int   i = sI[w][lane];
        if (s < gb) { gb = s; gk = i; }     // strict < = first min
    }

    // epilogue: wave wvu writes features [16*wvu, 16*wvu+16) for its lane's
    // token. CB0 literal per branch -> all f[] indices compile-time.
    const float4* eq4 = (const float4*)(eT + ((size_t)gk << 6)) + (wvu << 2);
    float* o0 = out_qwg + ((size_t)b << 18) + hw;
    float* o1 = out_q   + ((size_t)b << 18) + hw;

#define EPI_QUARTER(CB0)                                                          \
    {                                                                             \
        _Pragma("unroll")                                                         \
        for (int j = 0; j < 4; ++j) {                                             \
            float4 qv = eq4[j];                                                   \
            o0[(size_t)((CB0) + j*4 + 0) << HW_BITS] =                            \
                f[(CB0) + j*4 + 0] + (qv.x - f[(CB0) + j*4 + 0]);                 \
            o0[(size_t)((CB0) + j*4 + 1) << HW_BITS] =                            \
                f[(CB0) + j*4 + 1] + (qv.y - f[(CB0) + j*4 + 1]);                 \
            o0[(size_t)((CB0) + j*4 + 2) << HW_BITS] =                            \
                f[(CB0) + j*4 + 2] + (qv.z - f[(CB0) + j*4 + 2]);                 \
            o0[(size_t)((CB0) + j*4 + 3) << HW_BITS] =                            \
                f[(CB0) + j*4 + 3] + (qv.w - f[(CB0) + j*4 + 3]);                 \
            o1[(size_t)((CB0) + j*4 + 0) << HW_BITS] = qv.x;                      \
            o1[(size_t)((CB0) + j*4 + 1) << HW_BITS] = qv.y;                      \
            o1[(size_t)((CB0) + j*4 + 2) << HW_BITS] = qv.z;                      \
            o1[(size_t)((CB0) + j*4 + 3) << HW_BITS] = qv.w;                      \
        }                                                                         \
    }

    if (wvu == 0) {
        EPI_QUARTER(0)
        out_ind[tok] = (float)gk;
    } else if (wvu == 1) {
        EPI_QUARTER(16)
    } else if (wvu == 2) {
        EPI_QUARTER(32)
    } else {
        EPI_QUARTER(48)
    }
#undef EPI_QUARTER
}

extern "C" void kernel_launch(void* const* d_in, const int* in_sizes, int n_in,
                              void* d_out, int out_size, void* d_ws, size_t ws_size,
                              hipStream_t stream) {
    const float* x     = (const float*)d_in[0];
    const float* embed = (const float*)d_in[1];

    float* out     = (float*)d_out;
    float* out_qwg = out;                       // 8388608 f32
    float* out_q   = out + (size_t)8388608;     // 8388608 f32
    float* out_ind = out + (size_t)16777216;    // 131072 f32

    float* eT    = (float*)d_ws;                // 512*64 f32 = 128 KB
    float* norms = eT + K_CODES * C_DIM;        // 512 f32

    vq_prep<<<2, 256, 0, stream>>>(embed, eT, norms);
    vq_main<<<N_TOK / 64, 256, 0, stream>>>(x, eT, norms, out_qwg, out_q, out_ind);
}

// Round 5
// 245.047 us; speedup vs baseline: 3.5980x; 3.5980x over previous
//
#include <hip/hip_runtime.h>
#include <float.h>

// VQ: B=32, C=64, H=64, W=64, N_EMBED=512
#define C_DIM   64
#define K_CODES 512
#define HW_BITS 12              // HW = 4096
#define N_TOK   131072
#define TPB     64              // tokens per block
#define NW      8               // waves per block (512 threads), wave w owns codes [64w,64w+64)
#define LDS_PAD 68              // row stride (floats): 68*4=272 B = 17*16 -> float4-aligned, banks spread

// Prep: transpose embed [C][K] -> eT [K][C], and norms[k] = ||e_k||^2.
// (bit-identical to rounds 1-4)
__global__ __launch_bounds__(256) void vq_prep(const float* __restrict__ embed,
                                               float* __restrict__ eT,
                                               float* __restrict__ norms) {
    int k = blockIdx.x * blockDim.x + threadIdx.x;
    if (k >= K_CODES) return;
    float s = 0.f;
    #pragma unroll
    for (int c = 0; c < C_DIM; ++c) {
        float v = embed[c * K_CODES + k];   // coalesced across k
        eT[k * C_DIM + c] = v;
        s = fmaf(v, v, s);
    }
    norms[k] = s;
}

// lane = code. e-row lives in VGPRs (loop-invariant). f broadcast from LDS.
__global__ __launch_bounds__(512, 4) void vq_main(const float* __restrict__ x,
                                                  const float* __restrict__ eT,
                                                  const float* __restrict__ norms,
                                                  float* __restrict__ out_qwg,
                                                  float* __restrict__ out_q,
                                                  float* __restrict__ out_ind) {
    __shared__ float fL[TPB][LDS_PAD];   // token features, [t][c]
    __shared__ float sSc[TPB][NW];       // per-wave best score
    __shared__ int   sIx[TPB][NW];       // per-wave best code
    __shared__ int   gkL[TPB];           // merged winner per token

    const int tid  = threadIdx.x;
    const int lane = tid & 63;
    const int w    = tid >> 6;                 // wave id 0..7
    const int tok0 = blockIdx.x << 6;
    const int b    = tok0 >> HW_BITS;
    const int hw0  = tok0 & ((1 << HW_BITS) - 1);
    const float* xb = x + ((size_t)b << 18) + hw0;

    // ---- stage x tile -> fL[t][c] (16 KB), coalesced float4 along hw=token ----
    #pragma unroll
    for (int r = 0; r < 2; ++r) {
        int lin = tid + r * 512;               // 0..1023
        int c   = lin >> 4;                    // 0..63
        int tq  = (lin & 15) << 2;             // 0,4,...,60
        float4 v = *(const float4*)(xb + ((size_t)c << HW_BITS) + tq);
        fL[tq + 0][c] = v.x;
        fL[tq + 1][c] = v.y;
        fL[tq + 2][c] = v.z;
        fL[tq + 3][c] = v.w;
    }

    // ---- this lane's code row -> VGPRs (static indices only; stays resident) ----
    const int code = (w << 6) + lane;
    float e[C_DIM];
    {
        const float4* er = (const float4*)(eT + ((size_t)code << 6));
        #pragma unroll
        for (int c4 = 0; c4 < 16; ++c4) {
            float4 v = er[c4];
            e[c4 * 4 + 0] = v.x;
            e[c4 * 4 + 1] = v.y;
            e[c4 * 4 + 2] = v.z;
            e[c4 * 4 + 3] = v.w;
        }
    }
    const float nrm = norms[code];

    __syncthreads();

    // ---- main loop: per token, 16 broadcast ds_read_b128 + 64 fma + wave argmin ----
    #pragma unroll 1
    for (int t = 0; t < TPB; ++t) {
        const float4* f4 = (const float4*)(&fL[t][0]);  // wave-uniform -> broadcast
        float a0 = 0.f, a1 = 0.f, a2 = 0.f, a3 = 0.f;
        #pragma unroll
        for (int c4 = 0; c4 < 16; ++c4) {
            float4 fq = f4[c4];
            a0 = fmaf(fq.x, e[c4 * 4 + 0], a0);   // same c≡j (mod 4) chains as r1-r3
            a1 = fmaf(fq.y, e[c4 * 4 + 1], a1);
            a2 = fmaf(fq.z, e[c4 * 4 + 2], a2);
            a3 = fmaf(fq.w, e[c4 * 4 + 3], a3);
        }
        float score = fmaf(-2.f, (a0 + a1) + (a2 + a3), nrm);  // same formula as r1-r3

        // wave-wide min (exact), tie-break = lowest lane = lowest code
        float m = score;
        #pragma unroll
        for (int d = 32; d > 0; d >>= 1)
            m = fminf(m, __shfl_xor(m, d, 64));
        unsigned long long bal = __ballot(score == m);
        int winLane = __ffsll(bal) - 1;
        if (lane == 0) { sSc[t][w] = m; sIx[t][w] = (w << 6) + winLane; }
    }
    __syncthreads();

    // ---- merge 8 wave-winners per token (ascending w, strict < = first-min) ----
    if (w == 0) {
        float gb = sSc[lane][0];
        int   gk = sIx[lane][0];
        #pragma unroll
        for (int ww = 1; ww < NW; ++ww) {
            float s = sSc[lane][ww];
            if (s < gb) { gb = s; gk = sIx[lane][ww]; }
        }
        gkL[lane] = gk;
        out_ind[tok0 + lane] = (float)gk;
    }
    __syncthreads();

    // ---- epilogue: wave w writes channels [8w, 8w+8) for token = lane ----
    {
        const int t  = lane;
        const int gk = gkL[t];
        const float* qr = eT + ((size_t)gk << 6) + (w << 3);   // 16B-aligned
        float4 q0 = *(const float4*)(qr);
        float4 q1 = *(const float4*)(qr + 4);
        const float* fr = &fL[t][w << 3];                      // 16B-aligned
        float4 f0 = *(const float4*)(fr);
        float4 f1 = *(const float4*)(fr + 4);

        float* o0 = out_qwg + ((size_t)b << 18) + hw0 + t;     // lanes (t) coalesced
        float* o1 = out_q   + ((size_t)b << 18) + hw0 + t;
        const int c0 = w << 3;

        o0[(size_t)(c0 + 0) << HW_BITS] = f0.x + (q0.x - f0.x);
        o0[(size_t)(c0 + 1) << HW_BITS] = f0.y + (q0.y - f0.y);
        o0[(size_t)(c0 + 2) << HW_BITS] = f0.z + (q0.z - f0.z);
        o0[(size_t)(c0 + 3) << HW_BITS] = f0.w + (q0.w - f0.w);
        o0[(size_t)(c0 + 4) << HW_BITS] = f1.x + (q1.x - f1.x);
        o0[(size_t)(c0 + 5) << HW_BITS] = f1.y + (q1.y - f1.y);
        o0[(size_t)(c0 + 6) << HW_BITS] = f1.z + (q1.z - f1.z);
        o0[(size_t)(c0 + 7) << HW_BITS] = f1.w + (q1.w - f1.w);

        o1[(size_t)(c0 + 0) << HW_BITS] = q0.x;
        o1[(size_t)(c0 + 1) << HW_BITS] = q0.y;
        o1[(size_t)(c0 + 2) << HW_BITS] = q0.z;
        o1[(size_t)(c0 + 3) << HW_BITS] = q0.w;
        o1[(size_t)(c0 + 4) << HW_BITS] = q1.x;
        o1[(size_t)(c0 + 5) << HW_BITS] = q1.y;
        o1[(size_t)(c0 + 6) << HW_BITS] = q1.z;
        o1[(size_t)(c0 + 7) << HW_BITS] = q1.w;
    }
}

extern "C" void kernel_launch(void* const* d_in, const int* in_sizes, int n_in,
                              void* d_out, int out_size, void* d_ws, size_t ws_size,
                              hipStream_t stream) {
    const float* x     = (const float*)d_in[0];
    const float* embed = (const float*)d_in[1];

    float* out     = (float*)d_out;
    float* out_qwg = out;                       // 8388608 f32
    float* out_q   = out + (size_t)8388608;     // 8388608 f32
    float* out_ind = out + (size_t)16777216;    // 131072 f32

    float* eT    = (float*)d_ws;                // 512*64 f32 = 128 KB
    float* norms = eT + K_CODES * C_DIM;        // 512 f32

    vq_prep<<<2, 256, 0, stream>>>(embed, eT, norms);
    vq_main<<<N_TOK / TPB, 512, 0, stream>>>(x, eT, norms, out_qwg, out_q, out_ind);
}